// Round 1
// baseline (5601.930 us; speedup 1.0000x reference)
//
#include <hip/hip_runtime.h>

#define Hh 20
#define Tt 187
#define ROWS 64
#define NT 256

// sigmoid(x) = 1/(1+exp(-x)) via hw exp2/rcp
__device__ __forceinline__ float sigm(float x) {
  return __builtin_amdgcn_rcpf(1.0f + __builtin_amdgcn_exp2f(x * -1.44269504088896340736f));
}
// tanh(x) = 1 - 2/(exp(2x)+1)
__device__ __forceinline__ float tanh_(float x) {
  return 1.0f - 2.0f * __builtin_amdgcn_rcpf(1.0f + __builtin_amdgcn_exp2f(x * 2.88539008177792681472f));
}

// Broadcast lane R (0..3) of each aligned quad to all 4 lanes — DPP quad_perm, VALU pipe only.
template<int R>
__device__ __forceinline__ float qb(float v) {
  return __int_as_float(__builtin_amdgcn_mov_dpp(__float_as_int(v), R * 0x55, 0xF, 0xF, true));
}

// One LSTM cell step for this thread's 5 owned hidden units.
// WHH: LDS base of the 80x20 row-major weight block. ri[400*g + k] walks the f/g/o gate rows.
#define CELL(WHH, BI, BF, BG, BO, WXI, WXF, WXG, WXO, X)            \
  _Pragma("unroll")                                                 \
  for (int u = 0; u < 5; ++u) {                                     \
    const float* ri = (WHH) + (jb + u) * Hh;                        \
    float ai = fmaf((WXI)[u], (X), (BI)[u]);                        \
    float af = fmaf((WXF)[u], (X), (BF)[u]);                        \
    float ag = fmaf((WXG)[u], (X), (BG)[u]);                        \
    float ao = fmaf((WXO)[u], (X), (BO)[u]);                        \
    _Pragma("unroll")                                               \
    for (int k = 0; k < Hh; ++k) {                                  \
      float hk = h[k];                                              \
      ai = fmaf(ri[k], hk, ai);                                     \
      af = fmaf(ri[400 + k], hk, af);                               \
      ag = fmaf(ri[800 + k], hk, ag);                               \
      ao = fmaf(ri[1200 + k], hk, ao);                              \
    }                                                               \
    float ii = sigm(ai), ff = sigm(af), gg = tanh_(ag), oo = sigm(ao); \
    float cc = fmaf(ff, c[u], ii * gg);                             \
    c[u] = cc;                                                      \
    nh[u] = oo * tanh_(cc);                                         \
  }

// Share the 4 quad lanes' new-h slices so every lane holds full h[20].
#define SHARE()                                                     \
  _Pragma("unroll")                                                 \
  for (int u = 0; u < 5; ++u) {                                     \
    h[u]      = qb<0>(nh[u]);                                       \
    h[5 + u]  = qb<1>(nh[u]);                                       \
    h[10 + u] = qb<2>(nh[u]);                                       \
    h[15 + u] = qb<3>(nh[u]);                                       \
  }

extern "C" __global__ __launch_bounds__(NT, 2) void lstm_all(
    const float* __restrict__ inp,  const float* __restrict__ Wih1,
    const float* __restrict__ Whh1, const float* __restrict__ bih1,
    const float* __restrict__ bhh1, const float* __restrict__ Wih2,
    const float* __restrict__ Whh2, const float* __restrict__ bih2,
    const float* __restrict__ bhh2, const float* __restrict__ Wl,
    const float* __restrict__ bl,   float* __restrict__ out, int Btot)
{
  // weight LDS layout (floats):
  // [0,1600)  Whh1   [1600,1680) Wih1  [1680,1760) bih1+bhh1
  // [1760,3360) Whh2 [3360,3440) Wih2  [3440,3520) bih2+bhh2
  // [3520,3540) Wl   [3540] bl
  __shared__ float w[3541];
  __shared__ float buf[ROWS][Tt + 1];   // input tile, later reused for decoder outputs

  const int tid = threadIdx.x;

  for (int i = tid; i < 1600; i += NT) { w[i] = Whh1[i]; w[1760 + i] = Whh2[i]; }
  if (tid < 80) {
    w[1600 + tid] = Wih1[tid];
    w[1680 + tid] = bih1[tid] + bhh1[tid];
    w[3360 + tid] = Wih2[tid];
    w[3440 + tid] = bih2[tid] + bhh2[tid];
  }
  if (tid >= 80 && tid < 100) w[3440 + tid] = Wl[tid - 80];  // 3520..3539
  if (tid == 100) w[3540] = bl[0];

  const int row0 = blockIdx.x * ROWS;
  for (int i = tid; i < ROWS * Tt; i += NT) {
    int r = i / Tt, cc = i - r * Tt;
    buf[r][cc] = inp[(size_t)(row0 + r) * Tt + cc];
  }
  __syncthreads();

  const int q  = tid & 3;       // lane within quad: owns hidden [5q, 5q+5)
  const int lr = tid >> 2;      // local row
  const size_t b = (size_t)row0 + lr;
  const int jb = q * 5;

  const float* whh1 = w;
  const float* whh2 = w + 1760;

  // hoist per-thread loop-invariant biases + input weights into registers
  float bi1[5], bf1[5], bg1[5], bo1[5], wxi1[5], wxf1[5], wxg1[5], wxo1[5];
#pragma unroll
  for (int u = 0; u < 5; ++u) {
    int j = jb + u;
    bi1[u] = w[1680 + j]; bf1[u] = w[1700 + j]; bg1[u] = w[1720 + j]; bo1[u] = w[1740 + j];
    wxi1[u] = w[1600 + j]; wxf1[u] = w[1620 + j]; wxg1[u] = w[1640 + j]; wxo1[u] = w[1660 + j];
  }

  float h[Hh], c[5], nh[5];
#pragma unroll
  for (int k = 0; k < Hh; ++k) h[k] = 0.f;
#pragma unroll
  for (int u = 0; u < 5; ++u) { c[u] = 0.f; nh[u] = 0.f; }

  // ---------------- encoder ----------------
  for (int t = 0; t < Tt; ++t) {
    float x = buf[lr][t];
    CELL(whh1, bi1, bf1, bg1, bo1, wxi1, wxf1, wxg1, wxo1, x);
    SHARE();
  }

  // ---------------- log_softmax(he) ----------------
  {
    float m = h[0];
#pragma unroll
    for (int k = 1; k < Hh; ++k) m = fmaxf(m, h[k]);
    float ssum = 0.f;
#pragma unroll
    for (int k = 0; k < Hh; ++k)
      ssum += __builtin_amdgcn_exp2f((h[k] - m) * 1.44269504088896340736f);
    float lse = m + 0.69314718055994530942f * __builtin_amdgcn_logf(ssum);
    float* out2 = out + (size_t)Btot * Tt;
#pragma unroll
    for (int u = 0; u < 5; ++u) out2[b * Hh + jb + u] = nh[u] - lse;  // nh == owned he slice
  }

  // ---------------- decoder ----------------
  float bi2[5], bf2[5], bg2[5], bo2[5], wxi2[5], wxf2[5], wxg2[5], wxo2[5];
#pragma unroll
  for (int u = 0; u < 5; ++u) {
    int j = jb + u;
    bi2[u] = w[3440 + j]; bf2[u] = w[3460 + j]; bg2[u] = w[3480 + j]; bo2[u] = w[3500 + j];
    wxi2[u] = w[3360 + j]; wxf2[u] = w[3380 + j]; wxg2[u] = w[3400 + j]; wxo2[u] = w[3420 + j];
  }
  float wlr[Hh];
#pragma unroll
  for (int k = 0; k < Hh; ++k) wlr[k] = w[3520 + k];
  const float blv = w[3540];

  float ot = 0.f;
  for (int s = 0; s < Tt; ++s) {
    CELL(whh2, bi2, bf2, bg2, bo2, wxi2, wxf2, wxg2, wxo2, ot);
    SHARE();
    float acc = blv;
#pragma unroll
    for (int k = 0; k < Hh; ++k) acc = fmaf(wlr[k], h[k], acc);
    ot = sigm(acc);
    if (q == 0) buf[lr][186 - s] = ot;   // store pre-flipped
  }
  __syncthreads();

  // coalesced writeout of decoder outputs
  for (int i = tid; i < ROWS * Tt; i += NT) {
    int r = i / Tt, cc = i - r * Tt;
    out[(size_t)(row0 + r) * Tt + cc] = buf[r][cc];
  }
}

extern "C" void kernel_launch(void* const* d_in, const int* in_sizes, int n_in,
                              void* d_out, int out_size, void* d_ws, size_t ws_size,
                              hipStream_t stream) {
  const float* inp  = (const float*)d_in[0];
  const float* Wih1 = (const float*)d_in[1];
  const float* Whh1 = (const float*)d_in[2];
  const float* bih1 = (const float*)d_in[3];
  const float* bhh1 = (const float*)d_in[4];
  const float* Wih2 = (const float*)d_in[5];
  const float* Whh2 = (const float*)d_in[6];
  const float* bih2 = (const float*)d_in[7];
  const float* bhh2 = (const float*)d_in[8];
  const float* Wl   = (const float*)d_in[9];
  const float* bl   = (const float*)d_in[10];

  const int Btot = in_sizes[0] / Tt;        // 32768
  dim3 grid(Btot / ROWS), block(NT);
  hipLaunchKernelGGL(lstm_all, grid, block, 0, stream,
                     inp, Wih1, Whh1, bih1, bhh1, Wih2, Whh2, bih2, bhh2, Wl, bl,
                     (float*)d_out, Btot);
}

// Round 3
// 687.193 us; speedup vs baseline: 8.1519x; 8.1519x over previous
//
#include <hip/hip_runtime.h>

typedef _Float16 half2v __attribute__((ext_vector_type(2)));

#define Hh 20
#define Tt 187
#define NT 256
#define ROWS (NT / 4)

__device__ __forceinline__ float sigm(float x) {
  return __builtin_amdgcn_rcpf(1.0f + __builtin_amdgcn_exp2f(x * -1.44269504088896340736f));
}
__device__ __forceinline__ float tanh_(float x) {
  return 1.0f - 2.0f * __builtin_amdgcn_rcpf(1.0f + __builtin_amdgcn_exp2f(x * 2.88539008177792681472f));
}
template<int R>
__device__ __forceinline__ float qb(float v) {
  return __int_as_float(__builtin_amdgcn_mov_dpp(__float_as_int(v), R * 0x55, 0xF, 0xF, true));
}

__device__ __forceinline__ float fdot2f(half2v a, half2v b, float c) {
#if __has_builtin(__builtin_amdgcn_fdot2)
  return __builtin_amdgcn_fdot2(a, b, c, false);
#else
  return fmaf((float)a.y, (float)b.y, fmaf((float)a.x, (float)b.x, c));
#endif
}
__device__ __forceinline__ float fd2(half2v a, unsigned int wbits, float c) {
  return fdot2f(a, __builtin_bit_cast(half2v, wbits), c);
}
__device__ __forceinline__ unsigned int pkbits(float lo, float hi) {
  return __builtin_bit_cast(unsigned int, __builtin_amdgcn_cvt_pkrtz(lo, hi));
}
__device__ __forceinline__ half2v pk(float lo, float hi) {
  return __builtin_bit_cast(half2v, __builtin_amdgcn_cvt_pkrtz(lo, hi));
}

// 10x fdot2 over one 20-wide gate row; W4 = uint4* at the j-row base, O = 3*gate
#define DOT10(ACC, W4, O) do {                                        \
    uint4 A_ = (W4)[(O)], B_ = (W4)[(O) + 1], C_ = (W4)[(O) + 2];     \
    ACC = fd2(hh[0], A_.x, ACC); ACC = fd2(hh[1], A_.y, ACC);         \
    ACC = fd2(hh[2], A_.z, ACC); ACC = fd2(hh[3], A_.w, ACC);         \
    ACC = fd2(hh[4], B_.x, ACC); ACC = fd2(hh[5], B_.y, ACC);         \
    ACC = fd2(hh[6], B_.z, ACC); ACC = fd2(hh[7], B_.w, ACC);         \
    ACC = fd2(hh[8], C_.x, ACC); ACC = fd2(hh[9], C_.y, ACC);         \
  } while (0)

// LSTM cell for this thread's 5 owned units; weights from LDS uint array WP
// (layout [j][gate][12 uints]), x = f32 scalar input, state cst[5], out nh[5].
#define CELLD(WP, X) do {                                                      \
    _Pragma("unroll")                                                          \
    for (int u = 0; u < 5; ++u) {                                              \
      const uint4* w4 = reinterpret_cast<const uint4*>((WP) + (jb + u) * 48);  \
      float ai = fmaf(wxi[u], (X), bi[u]);                                     \
      float af = fmaf(wxf[u], (X), bf[u]);                                     \
      float ag = fmaf(wxg[u], (X), bg[u]);                                     \
      float ao = fmaf(wxo[u], (X), bo[u]);                                     \
      DOT10(ai, w4, 0); DOT10(af, w4, 3); DOT10(ag, w4, 6); DOT10(ao, w4, 9);  \
      float ii = sigm(ai), ff = sigm(af), gg = tanh_(ag), oo = sigm(ao);       \
      float cc = fmaf(ff, cst[u], ii * gg);                                    \
      cst[u] = cc;                                                             \
      nh[u] = oo * tanh_(cc);                                                  \
    }                                                                          \
  } while (0)

// Rebuild the packed-f16 full h vector from the quad's nh slices (DPP + pack).
#define SHAREPACK() do {                                                  \
    hh[0] = pk(qb<0>(nh[0]), qb<0>(nh[1]));                               \
    hh[1] = pk(qb<0>(nh[2]), qb<0>(nh[3]));                               \
    hh[2] = pk(qb<0>(nh[4]), qb<1>(nh[0]));                               \
    hh[3] = pk(qb<1>(nh[1]), qb<1>(nh[2]));                               \
    hh[4] = pk(qb<1>(nh[3]), qb<1>(nh[4]));                               \
    hh[5] = pk(qb<2>(nh[0]), qb<2>(nh[1]));                               \
    hh[6] = pk(qb<2>(nh[2]), qb<2>(nh[3]));                               \
    hh[7] = pk(qb<2>(nh[4]), qb<3>(nh[0]));                               \
    hh[8] = pk(qb<3>(nh[1]), qb<3>(nh[2]));                               \
    hh[9] = pk(qb<3>(nh[3]), qb<3>(nh[4]));                               \
  } while (0)

// Stage W[4H x H] f32 -> LDS packed-f16, layout [j 0..19][gate 0..3][12 uints]
#define STAGE_WHH(WP, WSRC) do {                                          \
    for (int t_ = tid; t_ < 800; t_ += NT) {                              \
      int j_ = t_ / 40, rem_ = t_ % 40, g_ = rem_ / 10, m_ = rem_ % 10;   \
      int rb_ = (g_ * 20 + j_) * 20 + 2 * m_;                             \
      (WP)[j_ * 48 + g_ * 12 + m_] = pkbits((WSRC)[rb_], (WSRC)[rb_ + 1]);\
    }                                                                     \
  } while (0)

#define HOIST_BW() do {                                                   \
    _Pragma("unroll")                                                     \
    for (int u = 0; u < 5; ++u) {                                         \
      int j = jb + u;                                                     \
      bi[u] = bsum[j];      bf[u] = bsum[20 + j];                         \
      bg[u] = bsum[40 + j]; bo[u] = bsum[60 + j];                         \
      wxi[u] = wih[j];      wxf[u] = wih[20 + j];                         \
      wxg[u] = wih[40 + j]; wxo[u] = wih[60 + j];                         \
    }                                                                     \
  } while (0)

// ============================= encoder =============================
extern "C" __global__ __launch_bounds__(NT, 2) void enc_kernel(
    const float* __restrict__ inp,  const float* __restrict__ Wih1,
    const float* __restrict__ Whh1, const float* __restrict__ bih1,
    const float* __restrict__ bhh1, float* __restrict__ out,
    float* __restrict__ ws_he, float* __restrict__ ws_ce, int Btot)
{
  __shared__ unsigned int wp[20 * 48];
  __shared__ float bsum[80], wih[80];
  __shared__ unsigned short ibuf[ROWS][Tt + 1];

  const int tid = threadIdx.x;
  const int row0 = blockIdx.x * ROWS;

  STAGE_WHH(wp, Whh1);
  if (tid < 80) { bsum[tid] = bih1[tid] + bhh1[tid]; wih[tid] = Wih1[tid]; }
  for (int i = tid; i < ROWS * Tt; i += NT) {
    int r = i / Tt, cc = i - r * Tt;
    union { _Float16 h; unsigned short s; } cv;
    cv.h = (_Float16)inp[(size_t)(row0 + r) * Tt + cc];
    ibuf[r][cc] = cv.s;
  }
  __syncthreads();

  const int q = tid & 3, lr = tid >> 2, jb = q * 5;
  const size_t b = (size_t)row0 + lr;

  float bi[5], bf[5], bg[5], bo[5], wxi[5], wxf[5], wxg[5], wxo[5];
  HOIST_BW();

  half2v hh[10];
  float cst[5], nh[5];
#pragma unroll
  for (int m = 0; m < 10; ++m) hh[m] = pk(0.f, 0.f);
#pragma unroll
  for (int u = 0; u < 5; ++u) { cst[u] = 0.f; nh[u] = 0.f; }

  for (int t = 0; t < Tt; ++t) {
    union { unsigned short s; _Float16 h; } cv; cv.s = ibuf[lr][t];
    float x = (float)cv.h;
    CELLD(wp, x);
    SHAREPACK();
  }

  // log_softmax over final h
  {
    float hf[20];
#pragma unroll
    for (int u = 0; u < 5; ++u) {
      hf[u]      = qb<0>(nh[u]);
      hf[5 + u]  = qb<1>(nh[u]);
      hf[10 + u] = qb<2>(nh[u]);
      hf[15 + u] = qb<3>(nh[u]);
    }
    float m = hf[0];
#pragma unroll
    for (int k = 1; k < 20; ++k) m = fmaxf(m, hf[k]);
    float ssum = 0.f;
#pragma unroll
    for (int k = 0; k < 20; ++k)
      ssum += __builtin_amdgcn_exp2f((hf[k] - m) * 1.44269504088896340736f);
    float lse = m + 0.69314718055994530942f * __builtin_amdgcn_logf(ssum);
    float* out2 = out + (size_t)Btot * Tt;
#pragma unroll
    for (int u = 0; u < 5; ++u) {
      out2[b * Hh + jb + u]  = nh[u] - lse;
      ws_he[b * Hh + jb + u] = nh[u];
      ws_ce[b * Hh + jb + u] = cst[u];
    }
  }
}

// ============================= decoder =============================
extern "C" __global__ __launch_bounds__(NT, 2) void dec_kernel(
    const float* __restrict__ Wih2, const float* __restrict__ Whh2,
    const float* __restrict__ bih2, const float* __restrict__ bhh2,
    const float* __restrict__ Wl,   const float* __restrict__ bl,
    const float* __restrict__ ws_he, const float* __restrict__ ws_ce,
    float* __restrict__ out, int Btot)
{
  __shared__ unsigned int wp[20 * 48];
  __shared__ float bsum[80], wih[80];
  __shared__ unsigned int wlp[10];
  __shared__ float blv_s;
  __shared__ float obuf[ROWS][48];

  const int tid = threadIdx.x;
  const int row0 = blockIdx.x * ROWS;

  STAGE_WHH(wp, Whh2);
  if (tid < 80) { bsum[tid] = bih2[tid] + bhh2[tid]; wih[tid] = Wih2[tid]; }
  if (tid >= 80 && tid < 90) wlp[tid - 80] = pkbits(Wl[2 * (tid - 80)], Wl[2 * (tid - 80) + 1]);
  if (tid == 90) blv_s = bl[0];
  __syncthreads();

  const int q = tid & 3, lr = tid >> 2, jb = q * 5;
  const size_t b = (size_t)row0 + lr;

  float bi[5], bf[5], bg[5], bo[5], wxi[5], wxf[5], wxg[5], wxo[5];
  HOIST_BW();

  half2v wl2[10];
#pragma unroll
  for (int m = 0; m < 10; ++m) wl2[m] = __builtin_bit_cast(half2v, wlp[m]);
  const float blv = blv_s;

  half2v hh[10];
  float cst[5], nh[5];
#pragma unroll
  for (int m = 0; m < 10; ++m) hh[m] = pk(ws_he[b * Hh + 2 * m], ws_he[b * Hh + 2 * m + 1]);
#pragma unroll
  for (int u = 0; u < 5; ++u) { cst[u] = ws_ce[b * Hh + jb + u]; nh[u] = 0.f; }

  float ot = 0.f;
  int s = 0;
  for (int ch = 0; ch < 4; ++ch) {
    const int base = ch * 47;
    const int len = (ch == 3) ? 46 : 47;
    for (int j = 0; j < len; ++j, ++s) {
      float x = ot;
      CELLD(wp, x);
      SHAREPACK();
      float acc = blv;
#pragma unroll
      for (int m = 0; m < 10; ++m) acc = fdot2f(hh[m], wl2[m], acc);
      ot = sigm(acc);
      if (q == 0) obuf[lr][j] = ot;
    }
    __syncthreads();
    for (int i = tid; i < ROWS * len; i += NT) {
      int r = i / len, j = i - r * len;
      out[(size_t)(row0 + r) * Tt + (186 - base - j)] = obuf[r][j];
    }
    __syncthreads();
  }
}

extern "C" void kernel_launch(void* const* d_in, const int* in_sizes, int n_in,
                              void* d_out, int out_size, void* d_ws, size_t ws_size,
                              hipStream_t stream) {
  const float* inp  = (const float*)d_in[0];
  const float* Wih1 = (const float*)d_in[1];
  const float* Whh1 = (const float*)d_in[2];
  const float* bih1 = (const float*)d_in[3];
  const float* bhh1 = (const float*)d_in[4];
  const float* Wih2 = (const float*)d_in[5];
  const float* Whh2 = (const float*)d_in[6];
  const float* bih2 = (const float*)d_in[7];
  const float* bhh2 = (const float*)d_in[8];
  const float* Wl   = (const float*)d_in[9];
  const float* bl   = (const float*)d_in[10];

  const int Btot = in_sizes[0] / Tt;  // 32768
  float* ws_he = (float*)d_ws;
  float* ws_ce = ws_he + (size_t)Btot * Hh;

  dim3 grid(Btot / ROWS), block(NT);
  hipLaunchKernelGGL(enc_kernel, grid, block, 0, stream,
                     inp, Wih1, Whh1, bih1, bhh1, (float*)d_out, ws_he, ws_ce, Btot);
  hipLaunchKernelGGL(dec_kernel, grid, block, 0, stream,
                     Wih2, Whh2, bih2, bhh2, Wl, bl, ws_he, ws_ce, (float*)d_out, Btot);
}

// Round 4
// 369.929 us; speedup vs baseline: 15.1432x; 1.8576x over previous
//
#include <hip/hip_runtime.h>

typedef __fp16 mf16x8 __attribute__((ext_vector_type(8)));
typedef float f32x4 __attribute__((ext_vector_type(4)));
typedef unsigned short u16;

#define Tt 187
#define STR 40   // u16 per hbuf row (k-slots 0..31 used, 16B-aligned rows, bank-friendly)
#define L2E 1.44269504088896340736f

__device__ __forceinline__ float sigm(float x) {
  return __builtin_amdgcn_rcpf(1.0f + __builtin_amdgcn_exp2f(x * -L2E));
}
__device__ __forceinline__ float tanh_(float x) {
  return 1.0f - 2.0f * __builtin_amdgcn_rcpf(1.0f + __builtin_amdgcn_exp2f(x * 2.0f * L2E));
}
__device__ __forceinline__ u16 toh(float x) {
  return __builtin_bit_cast(u16, (__fp16)x);
}

// Stage one layer's weights into per-lane MFMA fragments.
// A-operand (M-side = gate columns j): lane covers m-row j = 16*jt + (lane&15),
// k-slice = 8*(lane>>4) + kk.  Column order j = unit*4 + gate; W_aug[k][j]:
// k<20 -> Whh[gate*20+unit][k], k==20 -> Wih[gate*20+unit], else 0.
// Bias (C-init, D-layout): lane/reg i covers j = 16*jt + 4*(lane>>4) + i.
__device__ __forceinline__ void stage_layer(
    const float* __restrict__ Wih, const float* __restrict__ Whh,
    const float* __restrict__ bih, const float* __restrict__ bhh,
    int r, int g, mf16x8* A, f32x4* Bias)
{
#pragma unroll
  for (int jt = 0; jt < 5; ++jt) {
    const int unitA = 4 * jt + (r >> 2), gateA = r & 3;
    const int trow = gateA * 20 + unitA;          // torch row in [4H]
    mf16x8 av;
#pragma unroll
    for (int kk = 0; kk < 8; ++kk) {
      const int k = 8 * g + kk;
      float w = 0.f;
      if (k < 20)       w = Whh[trow * 20 + k];
      else if (k == 20) w = Wih[trow];
      av[kk] = (__fp16)w;
    }
    A[jt] = av;
    const int u = 4 * jt + g;                     // unit for D-side lane
    f32x4 bv;
#pragma unroll
    for (int i = 0; i < 4; ++i) bv[i] = bih[i * 20 + u] + bhh[i * 20 + u];
    Bias[jt] = bv;
  }
}

extern "C" __global__ __launch_bounds__(64) void lstm_fused(
    const float* __restrict__ inp,  const float* __restrict__ Wih1,
    const float* __restrict__ Whh1, const float* __restrict__ bih1,
    const float* __restrict__ bhh1, const float* __restrict__ Wih2,
    const float* __restrict__ Whh2, const float* __restrict__ bih2,
    const float* __restrict__ bhh2, const float* __restrict__ Wl,
    const float* __restrict__ bl,   float* __restrict__ out, int Btot)
{
  // hbuf[buf][r][k]: h^T staged f16; k = hidden 0..19, 20 = x, 21..31 = zero pad.
  __shared__ __align__(16) u16 hbuf[2][16 * STR];
  __shared__ __align__(16) u16 ibuf[16 * 188];
  __shared__ float obuf[16][47];

  const int lane = threadIdx.x;
  const int r = lane & 15;      // batch row within the wave's 16-row tile
  const int g = lane >> 4;      // k-chunk id (B-side) / row-group (D-side)
  const int row0 = blockIdx.x * 16;

  // ---- stage input tile (f32 -> f16), rows of this wave are contiguous ----
  {
    const float* src = inp + (size_t)row0 * Tt;
    for (int i = lane; i < 16 * Tt; i += 64) {
      int rr = i / Tt, t = i - rr * Tt;
      ibuf[rr * 188 + t] = toh(src[i]);
    }
  }
  // ---- zero both hbuf buffers (pads must be 0, not NaN) ----
  {
    unsigned int* hz = (unsigned int*)&hbuf[0][0];
    for (int i = lane; i < 16 * STR; i += 64) hz[i] = 0u;  // 2*16*STR u16 = 16*STR dwords
  }

  // ---- encoder weights -> registers ----
  mf16x8 A1[5]; f32x4 B1[5];
  stage_layer(Wih1, Whh1, bih1, bhh1, r, g, A1, B1);

  float c_[5], hn[5];
#pragma unroll
  for (int jt = 0; jt < 5; ++jt) { c_[jt] = 0.f; hn[jt] = 0.f; }

  __syncthreads();
  if (g == 2) hbuf[0][r * STR + 20] = ibuf[r * 188 + 0];   // x_0
  __syncthreads();

  const int rd_off = r * STR + 8 * g;   // u16 index of this lane's B-frag chunk
  const int wr_base = r * STR + g;      // + 4*jt per unit write

  // ================= encoder =================
  int cur = 0;
  for (int t = 0; t < Tt; ++t) {
    mf16x8 bf = __builtin_bit_cast(mf16x8, *(const uint4*)&hbuf[cur][rd_off]);
    const int nxt = cur ^ 1;
#pragma unroll
    for (int jt = 0; jt < 5; ++jt) {
      f32x4 acc = __builtin_amdgcn_mfma_f32_16x16x32_f16(A1[jt], bf, B1[jt], 0, 0, 0);
      float ii = sigm(acc[0]), ff = sigm(acc[1]);
      float gg = tanh_(acc[2]), oo = sigm(acc[3]);
      float cc = ff * c_[jt] + ii * gg;
      c_[jt] = cc;
      hn[jt] = oo * tanh_(cc);
      hbuf[nxt][wr_base + 4 * jt] = toh(hn[jt]);
    }
    if (g == 2 && t + 1 < Tt) hbuf[nxt][r * STR + 20] = ibuf[r * 188 + t + 1];
    __syncthreads();
    cur = nxt;
  }

  // ================= log_softmax(h_e) =================
  {
    float m = hn[0];
#pragma unroll
    for (int jt = 1; jt < 5; ++jt) m = fmaxf(m, hn[jt]);
    m = fmaxf(m, __shfl_xor(m, 16, 64));
    m = fmaxf(m, __shfl_xor(m, 32, 64));
    float s = 0.f;
#pragma unroll
    for (int jt = 0; jt < 5; ++jt) s += __builtin_amdgcn_exp2f((hn[jt] - m) * L2E);
    s += __shfl_xor(s, 16, 64);
    s += __shfl_xor(s, 32, 64);
    const float lse = m + 0.69314718055994530942f * __builtin_amdgcn_logf(s);
    float* out2 = out + (size_t)Btot * Tt;
#pragma unroll
    for (int jt = 0; jt < 5; ++jt)
      out2[(size_t)(row0 + r) * 20 + 4 * jt + g] = hn[jt] - lse;
  }

  // ---- decoder weights -> registers (after encoder: separate live ranges) ----
  mf16x8 A2[5]; f32x4 B2[5];
  stage_layer(Wih2, Whh2, bih2, bhh2, r, g, A2, B2);
  float wl[5];
#pragma unroll
  for (int jt = 0; jt < 5; ++jt) wl[jt] = Wl[4 * jt + g];
  const float blv = bl[0];

  if (g == 2) hbuf[cur][r * STR + 20] = 0;   // o_0 = 0 (slot holds stale x)
  __syncthreads();

  // ================= decoder =================
  for (int ch = 0; ch < 4; ++ch) {
    const int base = ch * 47;
    const int len = (ch == 3) ? 46 : 47;
    for (int j = 0; j < len; ++j) {
      mf16x8 bf = __builtin_bit_cast(mf16x8, *(const uint4*)&hbuf[cur][rd_off]);
      const int nxt = cur ^ 1;
#pragma unroll
      for (int jt = 0; jt < 5; ++jt) {
        f32x4 acc = __builtin_amdgcn_mfma_f32_16x16x32_f16(A2[jt], bf, B2[jt], 0, 0, 0);
        float ii = sigm(acc[0]), ff = sigm(acc[1]);
        float gg = tanh_(acc[2]), oo = sigm(acc[3]);
        float cc = ff * c_[jt] + ii * gg;
        c_[jt] = cc;
        hn[jt] = oo * tanh_(cc);
        hbuf[nxt][wr_base + 4 * jt] = toh(hn[jt]);
      }
      float p = hn[0] * wl[0];
#pragma unroll
      for (int jt = 1; jt < 5; ++jt) p = fmaf(hn[jt], wl[jt], p);
      p += __shfl_xor(p, 16, 64);
      p += __shfl_xor(p, 32, 64);
      const float ot = sigm(p + blv);
      if (g == 2) hbuf[nxt][r * STR + 20] = toh(ot);
      if (lane < 16) obuf[lane][j] = ot;        // lane == r for lane<16
      __syncthreads();
      cur = nxt;
    }
    // coalesced, pre-flipped flush of this chunk
    for (int rr = 0; rr < 16; ++rr) {
      if (lane < len)
        out[(size_t)(row0 + rr) * Tt + (186 - base - lane)] = obuf[rr][lane];
    }
    __syncthreads();
  }
}

extern "C" void kernel_launch(void* const* d_in, const int* in_sizes, int n_in,
                              void* d_out, int out_size, void* d_ws, size_t ws_size,
                              hipStream_t stream) {
  const float* inp  = (const float*)d_in[0];
  const float* Wih1 = (const float*)d_in[1];
  const float* Whh1 = (const float*)d_in[2];
  const float* bih1 = (const float*)d_in[3];
  const float* bhh1 = (const float*)d_in[4];
  const float* Wih2 = (const float*)d_in[5];
  const float* Whh2 = (const float*)d_in[6];
  const float* bih2 = (const float*)d_in[7];
  const float* bhh2 = (const float*)d_in[8];
  const float* Wl   = (const float*)d_in[9];
  const float* bl   = (const float*)d_in[10];

  const int Btot = in_sizes[0] / Tt;   // 32768
  dim3 grid(Btot / 16), block(64);
  hipLaunchKernelGGL(lstm_fused, grid, block, 0, stream,
                     inp, Wih1, Whh1, bih1, bhh1, Wih2, Whh2, bih2, bhh2, Wl, bl,
                     (float*)d_out, Btot);
}

// Round 5
// 313.691 us; speedup vs baseline: 17.8581x; 1.1793x over previous
//
#include <hip/hip_runtime.h>

typedef __fp16 mf16x8 __attribute__((ext_vector_type(8)));
typedef float f32x4 __attribute__((ext_vector_type(4)));

#define Tt 187
#define IST 189   // ibuf row stride (f32); 189 mod 32 = 29 -> 16 rows hit distinct banks
#define L2E 1.44269504088896340736f

__device__ __forceinline__ float sigm(float x) {
  return __builtin_amdgcn_rcpf(1.0f + __builtin_amdgcn_exp2f(x * -L2E));
}
__device__ __forceinline__ float tanh_(float x) {
  return 1.0f - 2.0f * __builtin_amdgcn_rcpf(1.0f + __builtin_amdgcn_exp2f(x * 2.0f * L2E));
}
__device__ __forceinline__ unsigned int pkbits(float lo, float hi) {
  return __builtin_bit_cast(unsigned int, __builtin_amdgcn_cvt_pkrtz(lo, hi));
}
// B fragment from this lane's own hn[5] (+ x in slot element 5): k-slot 8g+jt <-> unit 4jt+g
__device__ __forceinline__ mf16x8 mkbf(const float* hn, float xsel) {
  union { unsigned int u[4]; mf16x8 v; } cv;
  cv.u[0] = pkbits(hn[0], hn[1]);
  cv.u[1] = pkbits(hn[2], hn[3]);
  cv.u[2] = pkbits(hn[4], xsel);
  cv.u[3] = 0u;
  return cv.v;
}

// Stage one layer's weights into per-lane MFMA fragments.
// A lane (m = lane&15, ka = lane>>4): j = 16*jt + m -> unit 4*jt+(m>>2), gate m&3.
// k-slot 8*ka+kk: kk<5 -> input unit 4*kk+ka ; slot 21 -> x (Wih) ; else zero pad.
// Bias in D-layout: lane (r, g) reg i -> gate i of unit 4*jt+g.
__device__ __forceinline__ void stage_layer(
    const float* __restrict__ Wih, const float* __restrict__ Whh,
    const float* __restrict__ bih, const float* __restrict__ bhh,
    int m, int g, mf16x8* A, f32x4* Bias)
{
#pragma unroll
  for (int jt = 0; jt < 5; ++jt) {
    const int unitA = 4 * jt + (m >> 2), gateA = m & 3;
    const int trow = gateA * 20 + unitA;          // torch row in [4H]
    union { __fp16 h[8]; mf16x8 v; } av;
#pragma unroll
    for (int kk = 0; kk < 8; ++kk) {
      const int s = 8 * g + kk;                   // k-slot (A's k-group == lane>>4 == g)
      float w = 0.f;
      if (kk < 5)       w = Whh[trow * 20 + 4 * kk + g];
      else if (s == 21) w = Wih[trow];
      av.h[kk] = (__fp16)w;
    }
    A[jt] = av.v;
    const int u = 4 * jt + g;
    f32x4 bv;
#pragma unroll
    for (int i = 0; i < 4; ++i) bv[i] = bih[i * 20 + u] + bhh[i * 20 + u];
    Bias[jt] = bv;
  }
}

extern "C" __global__ __launch_bounds__(64) void lstm_fused(
    const float* __restrict__ inp,  const float* __restrict__ Wih1,
    const float* __restrict__ Whh1, const float* __restrict__ bih1,
    const float* __restrict__ bhh1, const float* __restrict__ Wih2,
    const float* __restrict__ Whh2, const float* __restrict__ bih2,
    const float* __restrict__ bhh2, const float* __restrict__ Wl,
    const float* __restrict__ bl,   float* __restrict__ out, int Btot)
{
  __shared__ __align__(16) float ibuf[16 * IST];   // read-only input tile

  const int lane = threadIdx.x;
  const int r = lane & 15;      // batch row within the wave's 16-row tile
  const int g = lane >> 4;      // k-chunk / unit-group id
  const int row0 = blockIdx.x * 16;

  // stage input tile, coalesced
  {
    const float* src = inp + (size_t)row0 * Tt;
    for (int i = lane; i < 16 * Tt; i += 64) {
      int rr = i / Tt, t = i - rr * Tt;
      ibuf[rr * IST + t] = src[i];
    }
  }

  mf16x8 A1[5]; f32x4 B1[5];
  stage_layer(Wih1, Whh1, bih1, bhh1, r, g, A1, B1);

  float c_[5], hn[5];
#pragma unroll
  for (int jt = 0; jt < 5; ++jt) { c_[jt] = 0.f; hn[jt] = 0.f; }

  __syncthreads();

  // ================= encoder (no LDS writes, no barriers) =================
  float xt = ibuf[r * IST];
  for (int t = 0; t < Tt; ++t) {
    float xnext = (t + 1 < Tt) ? ibuf[r * IST + t + 1] : 0.f;  // prefetch
    mf16x8 bf = mkbf(hn, (g == 2) ? xt : 0.f);
#pragma unroll
    for (int jt = 0; jt < 5; ++jt) {
      f32x4 acc = __builtin_amdgcn_mfma_f32_16x16x32_f16(A1[jt], bf, B1[jt], 0, 0, 0);
      float ii = sigm(acc[0]), ff = sigm(acc[1]);
      float gg = tanh_(acc[2]), oo = sigm(acc[3]);
      float cc = fmaf(ff, c_[jt], ii * gg);
      c_[jt] = cc;
      hn[jt] = oo * tanh_(cc);
    }
    xt = xnext;
  }

  // ================= log_softmax(h_e) =================
  {
    float m = hn[0];
#pragma unroll
    for (int jt = 1; jt < 5; ++jt) m = fmaxf(m, hn[jt]);
    m = fmaxf(m, __shfl_xor(m, 16, 64));
    m = fmaxf(m, __shfl_xor(m, 32, 64));
    float s = 0.f;
#pragma unroll
    for (int jt = 0; jt < 5; ++jt) s += __builtin_amdgcn_exp2f((hn[jt] - m) * L2E);
    s += __shfl_xor(s, 16, 64);
    s += __shfl_xor(s, 32, 64);
    const float lse = m + 0.69314718055994530942f * __builtin_amdgcn_logf(s);
    float* out2 = out + (size_t)Btot * Tt;
#pragma unroll
    for (int jt = 0; jt < 5; ++jt)
      out2[(size_t)(row0 + r) * 20 + 4 * jt + g] = hn[jt] - lse;
  }

  // ================= decoder =================
  mf16x8 A2[5]; f32x4 B2[5];
  stage_layer(Wih2, Whh2, bih2, bhh2, r, g, A2, B2);
  float wl[5];
#pragma unroll
  for (int jt = 0; jt < 5; ++jt) wl[jt] = Wl[4 * jt + g];
  const float blv = bl[0];

  float ot = 0.f;
  for (int s = 0; s < Tt; ++s) {
    mf16x8 bf = mkbf(hn, (g == 2) ? ot : 0.f);
#pragma unroll
    for (int jt = 0; jt < 5; ++jt) {
      f32x4 acc = __builtin_amdgcn_mfma_f32_16x16x32_f16(A2[jt], bf, B2[jt], 0, 0, 0);
      float ii = sigm(acc[0]), ff = sigm(acc[1]);
      float gg = tanh_(acc[2]), oo = sigm(acc[3]);
      float cc = fmaf(ff, c_[jt], ii * gg);
      c_[jt] = cc;
      hn[jt] = oo * tanh_(cc);
    }
    float p = hn[0] * wl[0];
#pragma unroll
    for (int jt = 1; jt < 5; ++jt) p = fmaf(hn[jt], wl[jt], p);
    p += __shfl_xor(p, 16, 64);
    p += __shfl_xor(p, 32, 64);
    ot = sigm(p + blv);
    if (g == 0) out[(size_t)(row0 + r) * Tt + (186 - s)] = ot;  // pre-flipped direct store
  }
}

extern "C" void kernel_launch(void* const* d_in, const int* in_sizes, int n_in,
                              void* d_out, int out_size, void* d_ws, size_t ws_size,
                              hipStream_t stream) {
  const float* inp  = (const float*)d_in[0];
  const float* Wih1 = (const float*)d_in[1];
  const float* Whh1 = (const float*)d_in[2];
  const float* bih1 = (const float*)d_in[3];
  const float* bhh1 = (const float*)d_in[4];
  const float* Wih2 = (const float*)d_in[5];
  const float* Whh2 = (const float*)d_in[6];
  const float* bih2 = (const float*)d_in[7];
  const float* bhh2 = (const float*)d_in[8];
  const float* Wl   = (const float*)d_in[9];
  const float* bl   = (const float*)d_in[10];

  const int Btot = in_sizes[0] / Tt;   // 32768
  dim3 grid(Btot / 16), block(64);
  hipLaunchKernelGGL(lstm_fused, grid, block, 0, stream,
                     inp, Wih1, Whh1, bih1, bhh1, Wih2, Whh2, bih2, bhh2, Wl, bl,
                     (float*)d_out, Btot);
}